// Round 1
// 148.958 us; speedup vs baseline: 1.0654x; 1.0654x over previous
//
#include <hip/hip_runtime.h>

typedef unsigned short u16;
typedef unsigned char u8;
typedef __attribute__((ext_vector_type(2))) float floatx2;
typedef __attribute__((ext_vector_type(4))) float floatx4;
typedef __attribute__((ext_vector_type(8))) __bf16 bf16x8;
typedef __attribute__((ext_vector_type(2))) unsigned short us2;
typedef __attribute__((ext_vector_type(4))) unsigned short us4;
typedef __attribute__((ext_vector_type(8))) unsigned short us8;
typedef __attribute__((ext_vector_type(2))) unsigned int u32x2;

static __device__ __forceinline__ float b2f(u16 v) {
    union { unsigned u; float f; } x; x.u = ((unsigned)v) << 16; return x.f;
}
static __device__ __forceinline__ u16 f2b(float f) {
    union { float f; unsigned u; } x; x.f = f;
    unsigned u = x.u;
    return (u16)((u + 0x7fffu + ((u >> 16) & 1u)) >> 16);
}

#define GLOAD_LDS16(g, l) __builtin_amdgcn_global_load_lds( \
    (const __attribute__((address_space(1))) void*)(g),     \
    (__attribute__((address_space(3))) void*)(l), 16, 0, 0)

#define CAP 64
#define SPILLMAX 4096

// Per-block dtype self-detection (see R5 notes): P(misdetect fp32) ~ 1e-65.
static __device__ __forceinline__ int detect_blk(const u16* __restrict__ p,
                                                 int nelem, int* sh) {
    if (threadIdx.x == 0) *sh = 0;
    __syncthreads();
    const int lim = nelem < 512 ? nelem : 512;
    int found = 0;
    for (int j = threadIdx.x; 2 * j < lim; j += 256) {
        unsigned v = p[2 * j] & 0x7fffu;
        if (v >= 0x4280u) found = 1;  // |bf16(bits)| >= 64.0
    }
    if (found) atomicOr(sh, 1);
    __syncthreads();
    return *sh;
}

// Bijective XCD-chunked swizzle (m204): blocks with the same output-tile row
// group land on one XCD so shared A-tiles hit that XCD's L2.
static __device__ __forceinline__ int xcd_swz(int L, int nwg) {
    const int q = nwg >> 3, r = nwg & 7;
    const int x = L & 7, i = L >> 3;
    return (x < r ? x * (q + 1) : r * (q + 1) + (x - r) * q) + i;
}

// ================= D1: buckets + all conversions (self-detecting) ================
__global__ __launch_bounds__(256) void k_d1(
    const int* __restrict__ src, const int* __restrict__ dst, int E, int Nn,
    int* __restrict__ cnt, int* __restrict__ bucket,
    int* __restrict__ nspill, int* __restrict__ spill,
    const void* __restrict__ h, const void* __restrict__ W1,
    const void* __restrict__ b1, const void* __restrict__ W2,
    const void* __restrict__ b2,
    u16* __restrict__ Hb, u16* __restrict__ W1T, u16* __restrict__ W2T,
    u16* __restrict__ b1c, u16* __restrict__ b2c, int* __restrict__ flags,
    int nFill, int nHb) {
    __shared__ u16 tile[32][33];
    __shared__ int sh;
    const int b = blockIdx.x;
    const int t = threadIdx.x;

    if (b < nFill) {  // -------- bucket fill --------
        int e = b * 256 + t;
        if (e < E) {
            int d = dst[e], s = src[e];
            if ((unsigned)d < (unsigned)Nn && (unsigned)s < (unsigned)Nn) {
                int p = atomicAdd(&cnt[d], 1);
                if (p < CAP) bucket[d * CAP + p] = s;
                else {
                    int q = atomicAdd(nspill, 1);
                    if (q < SPILLMAX) { spill[2 * q] = d; spill[2 * q + 1] = s; }
                }
            }
        }
        return;
    }
    if (b < nFill + nHb) {  // -------- Hb cvt --------
        const int f = detect_blk((const u16*)h, Nn * 512, &sh);
        int i = ((b - nFill) * 256 + t) * 8;
        if (i >= Nn * 512) return;
        if (f) {
            const float* s = (const float*)h;
            us8 o;
#pragma unroll
            for (int k = 0; k < 8; ++k) o[k] = f2b(s[i + k]);
            *(us8*)(Hb + i) = o;
        } else {
            *(us8*)(Hb + i) = *(const us8*)((const u16*)h + i);
        }
        return;
    }
    if (b < nFill + nHb + 512) {  // -------- W1 [1024,512] -> W1T [1024,512] --------
        const int f = detect_blk((const u16*)W1, 1024 * 512, &sh);
        int sub = b - nFill - nHb;
        int half = sub >> 8, idx = sub & 255;
        const int bx = (idx & 15) * 32, by = (idx >> 4) * 32;
        const int koff = half * 512, noff = half * 512;
        const int tx = t & 31, ty = t >> 5;
        for (int i = ty; i < 32; i += 8) {
            long id = (long)(koff + by + i) * 512 + (bx + tx);
            tile[i][tx] = f ? f2b(((const float*)W1)[id]) : ((const u16*)W1)[id];
        }
        __syncthreads();
        for (int i = ty; i < 32; i += 8)
            W1T[(long)(noff + bx + i) * 512 + (by + tx)] = tile[tx][i];
        return;
    }
    if (b < nFill + nHb + 640) {  // -------- W2 [1024,128] -> W2T [256,512] --------
        const int f = detect_blk((const u16*)W2, 1024 * 128, &sh);
        int sub = b - nFill - nHb - 512;
        int half = sub >> 6, idx = sub & 63;
        const int bx = (idx & 3) * 32, by = (idx >> 2) * 32;
        const int koff = half * 512, noff = half * 128;
        const int tx = t & 31, ty = t >> 5;
        for (int i = ty; i < 32; i += 8) {
            long id = (long)(koff + by + i) * 128 + (bx + tx);
            tile[i][tx] = f ? f2b(((const float*)W2)[id]) : ((const u16*)W2)[id];
        }
        __syncthreads();
        for (int i = ty; i < 32; i += 8)
            W2T[(long)(noff + bx + i) * 512 + (by + tx)] = tile[tx][i];
        return;
    }
    // -------- biases + out-dtype flag --------
    {
        const int f1 = detect_blk((const u16*)b1, 512, &sh);
        for (int i = t; i < 512; i += 256)
            b1c[i] = f1 ? f2b(((const float*)b1)[i]) : ((const u16*)b1)[i];
        const int f2 = detect_blk((const u16*)b2, 128, &sh);
        if (t < 128)
            b2c[t] = f2 ? f2b(((const float*)b2)[t]) : ((const u16*)b2)[t];
        const int fh = detect_blk((const u16*)h, Nn * 512, &sh);
        if (t == 0) flags[0] = fh;
    }
}

// ================= 64x256 GEMM accumulate core — 2-phase dbuf ====================
// T3-minimum pipeline: STAGE(t+1) into other LDS buffer, counted s_waitcnt
// vmcnt(5) (5 global_load_lds issued per wave per tile) + raw s_barrier.
// Prefetch loads stay in flight across the barrier (never drained to 0 in
// the main loop). Per-output K order identical to the old core ->
// bit-identical accumulation.
__device__ __forceinline__ void gemm_acc256(const u16* __restrict__ A,
                                            const u16* __restrict__ Bt,
                                            long brow, int bobs,
                                            floatx4 acc[4][4], u16* lA, u16* lB) {
    const int tid = threadIdx.x;
    const int wv = tid >> 6;
    const int ln = tid & 63;
    const int lrow = ln >> 2;
    const int lk = (ln & 3) * 8;
    const int m0 = ln & 15;
    const int kq = (ln >> 4) * 8;
    const int wc = wv * 64;

#pragma unroll
    for (int i = 0; i < 4; ++i)
#pragma unroll
        for (int j = 0; j < 4; ++j) acc[i][j] = (floatx4){0.f, 0.f, 0.f, 0.f};

    const u16* gA = A + (brow + wv * 16 + lrow) * 512 + lk;

    auto STAGE = [&](int kt, int sel) {
        u16* dA = lA + sel * 2048 + wv * 512;
        u16* dB = lB + sel * 8192;
        GLOAD_LDS16(gA + kt, dA);
#pragma unroll
        for (int ii = 0; ii < 4; ++ii) {
            const int c = ii * 4 + wv;
            GLOAD_LDS16(Bt + (long)(bobs + c * 16 + lrow) * 512 + kt + lk,
                        dB + c * 512);
        }
    };
    auto COMPUTE = [&](int sel) {
        const u16* rA = lA + sel * 2048;
        const u16* rB = lB + sel * 8192;
        bf16x8 af[4], bf[4];
#pragma unroll
        for (int i = 0; i < 4; ++i)
            af[i] = *(const bf16x8*)(rA + (i * 16 + m0) * 32 + kq);
#pragma unroll
        for (int j = 0; j < 4; ++j)
            bf[j] = *(const bf16x8*)(rB + (wc + j * 16 + m0) * 32 + kq);
#pragma unroll
        for (int i = 0; i < 4; ++i)
#pragma unroll
            for (int j = 0; j < 4; ++j)
                acc[i][j] = __builtin_amdgcn_mfma_f32_16x16x32_bf16(af[i], bf[j],
                                                                    acc[i][j], 0, 0, 0);
    };

    STAGE(0, 0);
    for (int t = 0; t < 15; ++t) {
        const int sel = t & 1;
        STAGE((t + 1) << 5, sel ^ 1);                      // prefetch next tile
        asm volatile("s_waitcnt vmcnt(5)" ::: "memory");   // tile t resident
        __builtin_amdgcn_s_barrier();
        COMPUTE(sel);
        asm volatile("s_waitcnt lgkmcnt(0)" ::: "memory"); // reads of buf done
        __builtin_amdgcn_s_barrier();
    }
    asm volatile("s_waitcnt vmcnt(0)" ::: "memory");
    __builtin_amdgcn_s_barrier();
    COMPUTE(1);  // t = 15
}

// ================= D2: GEMM1 64x256 ([C1s(bf16) | P1(fp8)] = Hb @ W1T^T) =========
// grid (ceil(M/64), 4) = 628 blocks; XCD-chunked swizzle keeps the 4 by-blocks
// of each bx on one XCD (A-tile L2 reuse).
__global__ __launch_bounds__(256) void k_gemm1_256(
    const u16* __restrict__ A, const u16* __restrict__ Bt,
    u16* __restrict__ C1s, u8* __restrict__ P1, int Mstore) {
    __shared__ __align__(16) u16 lA[2 * 64 * 32];
    __shared__ __align__(16) u16 lB[2 * 256 * 32];
    const int L = blockIdx.y * gridDim.x + blockIdx.x;
    const int T = xcd_swz(L, gridDim.x * gridDim.y);
    const int by = T & 3;                // 0..3
    const int bcol = by * 256;
    const long brow = (long)(T >> 2) * 64;
    floatx4 acc[4][4];
    gemm_acc256(A, Bt, brow, bcol, acc, lA, lB);

    const int ln = threadIdx.x & 63;
    const int wv = threadIdx.x >> 6;
    const int wc = wv * 64;
    const int m0 = ln & 15;
    const int q4 = (ln >> 4) * 4;
    if (by < 2) {  // self half (cols 0..511) -> bf16, ld 512
#pragma unroll
        for (int i = 0; i < 4; ++i)
#pragma unroll
            for (int r = 0; r < 4; ++r) {
                long row = brow + i * 16 + q4 + r;
                if (row < Mstore) {
#pragma unroll
                    for (int j = 0; j < 4; ++j)
                        C1s[row * 512 + (bcol + wc + j * 16 + m0)] = f2b(acc[i][j][r]);
                }
            }
    } else {       // agg half (cols 512..1023) -> fp8 e4m3 bytes, ld 512
        const int coff = bcol - 512;
#pragma unroll
        for (int i = 0; i < 4; ++i)
#pragma unroll
            for (int r = 0; r < 4; ++r) {
                long row = brow + i * 16 + q4 + r;
                if (row < Mstore) {
#pragma unroll
                    for (int j = 0; j < 4; ++j) {
                        float v = acc[i][j][r];
                        int pk = __builtin_amdgcn_cvt_pk_fp8_f32(v, v, 0, false);
                        P1[row * 512 + (coff + wc + j * 16 + m0)] = (u8)(pk & 0xff);
                    }
                }
            }
    }
}

// ================= 64x128 GEMM core — 2-phase dbuf (GEMM2) =======================
// 3 global_load_lds per wave per tile -> s_waitcnt vmcnt(3).
__device__ __forceinline__ void gemm_acc64(const u16* __restrict__ A,
                                           const u16* __restrict__ Bt,
                                           long brow, int bobs,
                                           floatx4 acc[4][2], u16* lA, u16* lB) {
    const int tid = threadIdx.x;
    const int wv = tid >> 6;
    const int ln = tid & 63;
    const int lrow = ln >> 2;
    const int lk = (ln & 3) * 8;
    const int m0 = ln & 15;
    const int kq = (ln >> 4) * 8;
    const int wc = wv * 32;

#pragma unroll
    for (int i = 0; i < 4; ++i)
#pragma unroll
        for (int j = 0; j < 2; ++j) acc[i][j] = (floatx4){0.f, 0.f, 0.f, 0.f};

    const u16* gA = A + (brow + wv * 16 + lrow) * 512 + lk;

    auto STAGE = [&](int kt, int sel) {
        u16* dA = lA + sel * 2048 + wv * 512;
        u16* dB = lB + sel * 4096;
        GLOAD_LDS16(gA + kt, dA);
#pragma unroll
        for (int ii = 0; ii < 2; ++ii) {
            const int c = ii * 4 + wv;
            GLOAD_LDS16(Bt + (long)(bobs + c * 16 + lrow) * 512 + kt + lk,
                        dB + c * 512);
        }
    };
    auto COMPUTE = [&](int sel) {
        const u16* rA = lA + sel * 2048;
        const u16* rB = lB + sel * 4096;
        bf16x8 af[4], bf[2];
#pragma unroll
        for (int i = 0; i < 4; ++i)
            af[i] = *(const bf16x8*)(rA + (i * 16 + m0) * 32 + kq);
#pragma unroll
        for (int j = 0; j < 2; ++j)
            bf[j] = *(const bf16x8*)(rB + (wc + j * 16 + m0) * 32 + kq);
#pragma unroll
        for (int i = 0; i < 4; ++i)
#pragma unroll
            for (int j = 0; j < 2; ++j)
                acc[i][j] = __builtin_amdgcn_mfma_f32_16x16x32_bf16(af[i], bf[j],
                                                                    acc[i][j], 0, 0, 0);
    };

    STAGE(0, 0);
    for (int t = 0; t < 15; ++t) {
        const int sel = t & 1;
        STAGE((t + 1) << 5, sel ^ 1);
        asm volatile("s_waitcnt vmcnt(3)" ::: "memory");
        __builtin_amdgcn_s_barrier();
        COMPUTE(sel);
        asm volatile("s_waitcnt lgkmcnt(0)" ::: "memory");
        __builtin_amdgcn_s_barrier();
    }
    asm volatile("s_waitcnt vmcnt(0)" ::: "memory");
    __builtin_amdgcn_s_barrier();
    COMPUTE(1);
}

// ================= D4: GEMM2 64x128 ([C2s|P2] = h1 @ W2T^T) ======================
__global__ __launch_bounds__(256) void k_gemm2_64(
    const u16* __restrict__ A, const u16* __restrict__ Bt,
    u16* __restrict__ C2s, u16* __restrict__ P2, int Mstore) {
    __shared__ __align__(16) u16 lA[2 * 64 * 32];
    __shared__ __align__(16) u16 lB[2 * 128 * 32];
    const int L = blockIdx.y * gridDim.x + blockIdx.x;
    const int T = xcd_swz(L, gridDim.x * gridDim.y);
    const int by = T & 1;
    const long brow = (long)(T >> 1) * 64;
    floatx4 acc[4][2];
    gemm_acc64(A, Bt, brow, by * 128, acc, lA, lB);

    u16* C = by ? P2 : C2s;
    const int ln = threadIdx.x & 63;
    const int wv = threadIdx.x >> 6;
    const int wc = wv * 32;
    const int m0 = ln & 15;
    const int q4 = (ln >> 4) * 4;
#pragma unroll
    for (int i = 0; i < 4; ++i)
#pragma unroll
        for (int r = 0; r < 4; ++r) {
            long row = brow + i * 16 + q4 + r;
            if (row < Mstore) {
#pragma unroll
                for (int j = 0; j < 2; ++j)
                    C[row * 128 + (wc + j * 16 + m0)] = f2b(acc[i][j][r]);
            }
        }
}

// ================= D3: h1 = relu(C1s + mean(P1fp8[nbrs]) + b1) ===================
// wave-per-node: one dwordx2 per edge; 8/4-deep gather unroll
__global__ __launch_bounds__(256) void agg_h1(const u8* __restrict__ P1,
                                              const u16* __restrict__ C1s,
                                              const u16* __restrict__ b1c,
                                              const int* __restrict__ cnt,
                                              const int* __restrict__ bucket,
                                              const int* __restrict__ nspill,
                                              const int* __restrict__ spill,
                                              u16* __restrict__ h1, int Nn) {
    const int n = blockIdx.x * 4 + (threadIdx.x >> 6);
    const int l = threadIdx.x & 63;
    if (n >= Nn) return;
    const int c = cnt[n];
    const int inb = c < CAP ? c : CAP;
    const int* bk = bucket + (long)n * CAP;
    float a0 = 0.f, a1 = 0.f, a2 = 0.f, a3 = 0.f;
    float a4 = 0.f, a5 = 0.f, a6 = 0.f, a7 = 0.f;
    int e = 0;
    for (; e + 7 < inb; e += 8) {
        u32x2 w[8];
#pragma unroll
        for (int q = 0; q < 8; ++q) {
            int s = bk[e + q];
            w[q] = *(const u32x2*)(P1 + (long)s * 512 + l * 8);
        }
#pragma unroll
        for (int q = 0; q < 8; ++q) {
            floatx2 f0 = __builtin_amdgcn_cvt_pk_f32_fp8(w[q][0], false);
            floatx2 f1 = __builtin_amdgcn_cvt_pk_f32_fp8(w[q][0], true);
            floatx2 f2 = __builtin_amdgcn_cvt_pk_f32_fp8(w[q][1], false);
            floatx2 f3 = __builtin_amdgcn_cvt_pk_f32_fp8(w[q][1], true);
            a0 += f0[0]; a1 += f0[1]; a2 += f1[0]; a3 += f1[1];
            a4 += f2[0]; a5 += f2[1]; a6 += f3[0]; a7 += f3[1];
        }
    }
    for (; e + 3 < inb; e += 4) {
        u32x2 w[4];
#pragma unroll
        for (int q = 0; q < 4; ++q) {
            int s = bk[e + q];
            w[q] = *(const u32x2*)(P1 + (long)s * 512 + l * 8);
        }
#pragma unroll
        for (int q = 0; q < 4; ++q) {
            floatx2 f0 = __builtin_amdgcn_cvt_pk_f32_fp8(w[q][0], false);
            floatx2 f1 = __builtin_amdgcn_cvt_pk_f32_fp8(w[q][0], true);
            floatx2 f2 = __builtin_amdgcn_cvt_pk_f32_fp8(w[q][1], false);
            floatx2 f3 = __builtin_amdgcn_cvt_pk_f32_fp8(w[q][1], true);
            a0 += f0[0]; a1 += f0[1]; a2 += f1[0]; a3 += f1[1];
            a4 += f2[0]; a5 += f2[1]; a6 += f3[0]; a7 += f3[1];
        }
    }
    for (; e < inb; ++e) {
        int s = bk[e];
        u32x2 w = *(const u32x2*)(P1 + (long)s * 512 + l * 8);
        floatx2 f0 = __builtin_amdgcn_cvt_pk_f32_fp8(w[0], false);
        floatx2 f1 = __builtin_amdgcn_cvt_pk_f32_fp8(w[0], true);
        floatx2 f2 = __builtin_amdgcn_cvt_pk_f32_fp8(w[1], false);
        floatx2 f3 = __builtin_amdgcn_cvt_pk_f32_fp8(w[1], true);
        a0 += f0[0]; a1 += f0[1]; a2 += f1[0]; a3 += f1[1];
        a4 += f2[0]; a5 += f2[1]; a6 += f3[0]; a7 += f3[1];
    }
    const int ns = *nspill;             // 0 in practice
    if (ns > 0) {
        int lim = ns < SPILLMAX ? ns : SPILLMAX;
        for (int q = 0; q < lim; ++q) {
            if (spill[2 * q] == n) {
                int s = spill[2 * q + 1];
                u32x2 w = *(const u32x2*)(P1 + (long)s * 512 + l * 8);
                floatx2 f0 = __builtin_amdgcn_cvt_pk_f32_fp8(w[0], false);
                floatx2 f1 = __builtin_amdgcn_cvt_pk_f32_fp8(w[0], true);
                floatx2 f2 = __builtin_amdgcn_cvt_pk_f32_fp8(w[1], false);
                floatx2 f3 = __builtin_amdgcn_cvt_pk_f32_fp8(w[1], true);
                a0 += f0[0]; a1 += f0[1]; a2 += f1[0]; a3 += f1[1];
                a4 += f2[0]; a5 += f2[1]; a6 += f3[0]; a7 += f3[1];
            }
        }
    }
    float inv = 1.0f / (float)(c > 1 ? c : 1);
    us8 sf = *(const us8*)(C1s + (long)n * 512 + l * 8);
    us8 bv = *(const us8*)(b1c + l * 8);
    us8 o;
    o[0] = f2b(fmaxf(b2f(sf[0]) + a0 * inv + b2f(bv[0]), 0.f));
    o[1] = f2b(fmaxf(b2f(sf[1]) + a1 * inv + b2f(bv[1]), 0.f));
    o[2] = f2b(fmaxf(b2f(sf[2]) + a2 * inv + b2f(bv[2]), 0.f));
    o[3] = f2b(fmaxf(b2f(sf[3]) + a3 * inv + b2f(bv[3]), 0.f));
    o[4] = f2b(fmaxf(b2f(sf[4]) + a4 * inv + b2f(bv[4]), 0.f));
    o[5] = f2b(fmaxf(b2f(sf[5]) + a5 * inv + b2f(bv[5]), 0.f));
    o[6] = f2b(fmaxf(b2f(sf[6]) + a6 * inv + b2f(bv[6]), 0.f));
    o[7] = f2b(fmaxf(b2f(sf[7]) + a7 * inv + b2f(bv[7]), 0.f));
    *(us8*)(h1 + (long)n * 512 + l * 8) = o;
}

// ================= D5: out = C2s + mean(P2[nbrs]) + b2 ===========================
__global__ __launch_bounds__(256) void agg_out(const u16* __restrict__ P2,
                                               const u16* __restrict__ C2s,
                                               const u16* __restrict__ b2c,
                                               const int* __restrict__ cnt,
                                               const int* __restrict__ bucket,
                                               const int* __restrict__ nspill,
                                               const int* __restrict__ spill,
                                               void* __restrict__ outv, int Nn,
                                               const int* __restrict__ flags) {
    const int n = blockIdx.x * 4 + (threadIdx.x >> 6);
    const int l = threadIdx.x & 63;
    if (n >= Nn) return;
    const int c = cnt[n];
    const int inb = c < CAP ? c : CAP;
    const int* bk = bucket + (long)n * CAP;
    float a0 = 0.f, a1 = 0.f;
    int e = 0;
    for (; e + 3 < inb; e += 4) {
        int s0 = bk[e], s1 = bk[e + 1], s2 = bk[e + 2], s3 = bk[e + 3];
        us2 v0 = *(const us2*)(P2 + (long)s0 * 128 + l * 2);
        us2 v1 = *(const us2*)(P2 + (long)s1 * 128 + l * 2);
        us2 v2 = *(const us2*)(P2 + (long)s2 * 128 + l * 2);
        us2 v3 = *(const us2*)(P2 + (long)s3 * 128 + l * 2);
        a0 += (b2f(v0[0]) + b2f(v1[0])) + (b2f(v2[0]) + b2f(v3[0]));
        a1 += (b2f(v0[1]) + b2f(v1[1])) + (b2f(v2[1]) + b2f(v3[1]));
    }
    for (; e < inb; ++e) {
        int s0 = bk[e];
        us2 v0 = *(const us2*)(P2 + (long)s0 * 128 + l * 2);
        a0 += b2f(v0[0]); a1 += b2f(v0[1]);
    }
    const int ns = *nspill;
    if (ns > 0) {
        int lim = ns < SPILLMAX ? ns : SPILLMAX;
        for (int q = 0; q < lim; ++q) {
            if (spill[2 * q] == n) {
                int s0 = spill[2 * q + 1];
                us2 v0 = *(const us2*)(P2 + (long)s0 * 128 + l * 2);
                a0 += b2f(v0[0]); a1 += b2f(v0[1]);
            }
        }
    }
    float inv = 1.0f / (float)(c > 1 ? c : 1);
    us2 sf = *(const us2*)(C2s + (long)n * 128 + l * 2);
    us2 bv = *(const us2*)(b2c + l * 2);
    float o0 = b2f(sf[0]) + a0 * inv + b2f(bv[0]);
    float o1 = b2f(sf[1]) + a1 * inv + b2f(bv[1]);
    if (flags[0]) {
        float* o = (float*)outv + (long)n * 128 + l * 2;
        o[0] = o0; o[1] = o1;
    } else {
        us2 ob; ob[0] = f2b(o0); ob[1] = f2b(o1);
        *(us2*)((u16*)outv + (long)n * 128 + l * 2) = ob;
    }
}

// ================= launch ========================================================
extern "C" void kernel_launch(void* const* d_in, const int* in_sizes, int n_in,
                              void* d_out, int out_size, void* d_ws, size_t ws_size,
                              hipStream_t stream) {
    const int D = 512, NCLS = 128;
    const int Nn = in_sizes[0] / D;            // 10000
    const int E  = in_sizes[5];                // 160000
    const int mtiles = (Nn + 127) / 128;       // 79
    const int mt64 = (Nn + 63) / 64;           // 157
    const int Mpad = mtiles * 128;             // 10112
    const int nFill = (E + 255) / 256;         // 625
    const int nHb = (Nn * D / 8 + 255) / 256;  // 2500

    const int* src = (const int*)d_in[5];
    const int* dst = (const int*)d_in[6];

    char* p = (char*)d_ws;
    u16* Hb  = (u16*)p; p += (size_t)Mpad * D * 2;
    u16* h1  = (u16*)p; p += (size_t)Mpad * D * 2;
    u16* C1s = (u16*)p; p += (size_t)Mpad * D * 2;
    u8*  P1  = (u8*)p;  p += (size_t)Mpad * D;        // fp8 e4m3
    u16* C2s = (u16*)p; p += (size_t)Mpad * NCLS * 2;
    u16* P2  = (u16*)p; p += (size_t)Mpad * NCLS * 2;
    u16* W1T = (u16*)p; p += (size_t)1024 * D * 2;
    u16* W2T = (u16*)p; p += (size_t)256 * D * 2;
    u16* b1c = (u16*)p; p += 1024;
    u16* b2c = (u16*)p; p += 1024;
    int* flags  = (int*)p; p += 256;
    int* cnt    = (int*)p; p += (size_t)(Nn + 60) * 4;
    int* nspill = cnt + Nn;
    int* bucket = (int*)p; p += (size_t)Nn * CAP * 4;
    int* spill  = (int*)p; p += (size_t)SPILLMAX * 2 * 4;

    hipMemsetAsync(cnt, 0, (size_t)(Nn + 60) * 4, stream);

    // D1: buckets + all conversions
    k_d1<<<nFill + nHb + 641, 256, 0, stream>>>(
        src, dst, E, Nn, cnt, bucket, nspill, spill,
        d_in[0], d_in[1], d_in[2], d_in[3], d_in[4],
        Hb, W1T, W2T, b1c, b2c, flags, nFill, nHb);

    // D2: [C1s(bf16) | P1(fp8)] = Hb @ W1T^T  [64x256 tiles, 628 blocks, 2-phase]
    k_gemm1_256<<<dim3(mt64, 4), 256, 0, stream>>>(Hb, W1T, C1s, P1, Nn);

    // D3: h1 = relu(C1s + mean(P1[nbrs]) + b1)  [wave-per-node]
    agg_h1<<<(Nn + 3) / 4, 256, 0, stream>>>(P1, C1s, b1c, cnt, bucket,
                                             nspill, spill, h1, Nn);

    // D4: [C2s|P2] = h1 @ W2T^T  [64x128 tiles, 314 blocks, 2-phase]
    k_gemm2_64<<<dim3(mt64, 2), 256, 0, stream>>>(h1, W2T, C2s, P2, Nn);

    // D5: out = C2s + mean(P2[nbrs]) + b2
    agg_out<<<(Nn + 3) / 4, 256, 0, stream>>>(P2, C2s, b2c, cnt, bucket,
                                              nspill, spill, d_out, Nn, flags);
}

// Round 2
// 148.148 us; speedup vs baseline: 1.0712x; 1.0055x over previous
//
#include <hip/hip_runtime.h>

typedef unsigned short u16;
typedef unsigned char u8;
typedef __attribute__((ext_vector_type(2))) float floatx2;
typedef __attribute__((ext_vector_type(4))) float floatx4;
typedef __attribute__((ext_vector_type(8))) __bf16 bf16x8;
typedef __attribute__((ext_vector_type(2))) unsigned short us2;
typedef __attribute__((ext_vector_type(4))) unsigned short us4;
typedef __attribute__((ext_vector_type(8))) unsigned short us8;
typedef __attribute__((ext_vector_type(2))) unsigned int u32x2;

static __device__ __forceinline__ float b2f(u16 v) {
    union { unsigned u; float f; } x; x.u = ((unsigned)v) << 16; return x.f;
}
static __device__ __forceinline__ u16 f2b(float f) {
    union { float f; unsigned u; } x; x.f = f;
    unsigned u = x.u;
    return (u16)((u + 0x7fffu + ((u >> 16) & 1u)) >> 16);
}

#define GLOAD_LDS16(g, l) __builtin_amdgcn_global_load_lds( \
    (const __attribute__((address_space(1))) void*)(g),     \
    (__attribute__((address_space(3))) void*)(l), 16, 0, 0)

#define CAP 64
#define SPILLMAX 4096

// Per-block dtype self-detection (see R5 notes): P(misdetect fp32) ~ 1e-65.
static __device__ __forceinline__ int detect_blk(const u16* __restrict__ p,
                                                 int nelem, int* sh) {
    if (threadIdx.x == 0) *sh = 0;
    __syncthreads();
    const int lim = nelem < 512 ? nelem : 512;
    int found = 0;
    for (int j = threadIdx.x; 2 * j < lim; j += 256) {
        unsigned v = p[2 * j] & 0x7fffu;
        if (v >= 0x4280u) found = 1;  // |bf16(bits)| >= 64.0
    }
    if (found) atomicOr(sh, 1);
    __syncthreads();
    return *sh;
}

// Bijective XCD-chunked swizzle (m204): blocks with the same output-tile row
// group land on one XCD so shared A-tiles hit that XCD's L2.
static __device__ __forceinline__ int xcd_swz(int L, int nwg) {
    const int q = nwg >> 3, r = nwg & 7;
    const int x = L & 7, i = L >> 3;
    return (x < r ? x * (q + 1) : r * (q + 1) + (x - r) * q) + i;
}

// ================= D1: buckets + all conversions (self-detecting) ================
__global__ __launch_bounds__(256) void k_d1(
    const int* __restrict__ src, const int* __restrict__ dst, int E, int Nn,
    int* __restrict__ cnt, int* __restrict__ bucket,
    int* __restrict__ nspill, int* __restrict__ spill,
    const void* __restrict__ h, const void* __restrict__ W1,
    const void* __restrict__ b1, const void* __restrict__ W2,
    const void* __restrict__ b2,
    u16* __restrict__ Hb, u16* __restrict__ W1T, u16* __restrict__ W2T,
    u16* __restrict__ b1c, u16* __restrict__ b2c, int* __restrict__ flags,
    int nFill, int nHb) {
    __shared__ u16 tile[32][33];
    __shared__ int sh;
    const int b = blockIdx.x;
    const int t = threadIdx.x;

    if (b < nFill) {  // -------- bucket fill --------
        int e = b * 256 + t;
        if (e < E) {
            int d = dst[e], s = src[e];
            if ((unsigned)d < (unsigned)Nn && (unsigned)s < (unsigned)Nn) {
                int p = atomicAdd(&cnt[d], 1);
                if (p < CAP) bucket[d * CAP + p] = s;
                else {
                    int q = atomicAdd(nspill, 1);
                    if (q < SPILLMAX) { spill[2 * q] = d; spill[2 * q + 1] = s; }
                }
            }
        }
        return;
    }
    if (b < nFill + nHb) {  // -------- Hb cvt --------
        const int f = detect_blk((const u16*)h, Nn * 512, &sh);
        int i = ((b - nFill) * 256 + t) * 8;
        if (i >= Nn * 512) return;
        if (f) {
            const float* s = (const float*)h;
            us8 o;
#pragma unroll
            for (int k = 0; k < 8; ++k) o[k] = f2b(s[i + k]);
            *(us8*)(Hb + i) = o;
        } else {
            *(us8*)(Hb + i) = *(const us8*)((const u16*)h + i);
        }
        return;
    }
    if (b < nFill + nHb + 512) {  // -------- W1 [1024,512] -> W1T [1024,512] --------
        const int f = detect_blk((const u16*)W1, 1024 * 512, &sh);
        int sub = b - nFill - nHb;
        int half = sub >> 8, idx = sub & 255;
        const int bx = (idx & 15) * 32, by = (idx >> 4) * 32;
        const int koff = half * 512, noff = half * 512;
        const int tx = t & 31, ty = t >> 5;
        for (int i = ty; i < 32; i += 8) {
            long id = (long)(koff + by + i) * 512 + (bx + tx);
            tile[i][tx] = f ? f2b(((const float*)W1)[id]) : ((const u16*)W1)[id];
        }
        __syncthreads();
        for (int i = ty; i < 32; i += 8)
            W1T[(long)(noff + bx + i) * 512 + (by + tx)] = tile[tx][i];
        return;
    }
    if (b < nFill + nHb + 640) {  // -------- W2 [1024,128] -> W2T [256,512] --------
        const int f = detect_blk((const u16*)W2, 1024 * 128, &sh);
        int sub = b - nFill - nHb - 512;
        int half = sub >> 6, idx = sub & 63;
        const int bx = (idx & 3) * 32, by = (idx >> 2) * 32;
        const int koff = half * 512, noff = half * 128;
        const int tx = t & 31, ty = t >> 5;
        for (int i = ty; i < 32; i += 8) {
            long id = (long)(koff + by + i) * 128 + (bx + tx);
            tile[i][tx] = f ? f2b(((const float*)W2)[id]) : ((const u16*)W2)[id];
        }
        __syncthreads();
        for (int i = ty; i < 32; i += 8)
            W2T[(long)(noff + bx + i) * 512 + (by + tx)] = tile[tx][i];
        return;
    }
    // -------- biases + out-dtype flag --------
    {
        const int f1 = detect_blk((const u16*)b1, 512, &sh);
        for (int i = t; i < 512; i += 256)
            b1c[i] = f1 ? f2b(((const float*)b1)[i]) : ((const u16*)b1)[i];
        const int f2 = detect_blk((const u16*)b2, 128, &sh);
        if (t < 128)
            b2c[t] = f2 ? f2b(((const float*)b2)[t]) : ((const u16*)b2)[t];
        const int fh = detect_blk((const u16*)h, Nn * 512, &sh);
        if (t == 0) flags[0] = fh;
    }
}

// ================= 128x128 GEMM core — depth-2 prefetch, 3 LDS buffers ===========
// 4 waves in 2x2 layout, each wave a 64x64 output quadrant (4x4 16x16 frags).
// Per tile per wave: 2 A-chunks + 2 B-chunks staged (global_load_lds x4).
// Steady state: tiles t+1, t+2 in flight; vmcnt(8) waits only for tile t ->
// staging latency gets ~2 full phases to land. K order per output unchanged.
__device__ __forceinline__ void gemm_acc128(const u16* __restrict__ A,
                                            const u16* __restrict__ Bt,
                                            long brow, int bobs,
                                            floatx4 acc[4][4], u16* lA, u16* lB) {
    const int tid = threadIdx.x;
    const int wv = tid >> 6;
    const int ln = tid & 63;
    const int lrow = ln >> 2;       // 0..15
    const int lk = (ln & 3) * 8;    // 0,8,16,24
    const int m0 = ln & 15;
    const int kq = (ln >> 4) * 8;
    const int wr = (wv >> 1) * 64;  // wave row quadrant
    const int wc = (wv & 1) * 64;   // wave col quadrant

#pragma unroll
    for (int i = 0; i < 4; ++i)
#pragma unroll
        for (int j = 0; j < 4; ++j) acc[i][j] = (floatx4){0.f, 0.f, 0.f, 0.f};

    auto STAGE = [&](int kt, int sel) {
        u16* dA = lA + sel * 4096;  // 128x32 u16 per buffer
        u16* dB = lB + sel * 4096;
#pragma unroll
        for (int ii = 0; ii < 2; ++ii) {
            const int c = ii * 4 + wv;  // chunks wv, wv+4 of 0..7
            GLOAD_LDS16(A + (brow + c * 16 + lrow) * 512 + kt + lk, dA + c * 512);
            GLOAD_LDS16(Bt + (long)(bobs + c * 16 + lrow) * 512 + kt + lk,
                        dB + c * 512);
        }
    };
    auto COMPUTE = [&](int sel) {
        const u16* rA = lA + sel * 4096;
        const u16* rB = lB + sel * 4096;
        bf16x8 af[4], bf[4];
#pragma unroll
        for (int i = 0; i < 4; ++i)
            af[i] = *(const bf16x8*)(rA + (wr + i * 16 + m0) * 32 + kq);
#pragma unroll
        for (int j = 0; j < 4; ++j)
            bf[j] = *(const bf16x8*)(rB + (wc + j * 16 + m0) * 32 + kq);
#pragma unroll
        for (int i = 0; i < 4; ++i)
#pragma unroll
            for (int j = 0; j < 4; ++j)
                acc[i][j] = __builtin_amdgcn_mfma_f32_16x16x32_bf16(af[i], bf[j],
                                                                    acc[i][j], 0, 0, 0);
    };

    STAGE(0, 0);
    STAGE(32, 1);
    int cur = 0, nxt = 1, fut = 2;
    for (int t = 0; t < 14; ++t) {
        STAGE((t + 2) << 5, fut);                          // 2-deep prefetch
        asm volatile("s_waitcnt vmcnt(8)" ::: "memory");   // tile t resident
        __builtin_amdgcn_s_barrier();
        COMPUTE(cur);
        asm volatile("s_waitcnt lgkmcnt(0)" ::: "memory");
        __builtin_amdgcn_s_barrier();
        int tmp = cur; cur = nxt; nxt = fut; fut = tmp;
    }
    asm volatile("s_waitcnt vmcnt(4)" ::: "memory");       // t = 14
    __builtin_amdgcn_s_barrier();
    COMPUTE(cur);
    asm volatile("s_waitcnt lgkmcnt(0)" ::: "memory");
    __builtin_amdgcn_s_barrier();
    asm volatile("s_waitcnt vmcnt(0)" ::: "memory");       // t = 15
    __builtin_amdgcn_s_barrier();
    COMPUTE(nxt);
}

// ================= D2: GEMM1 128x128 ([C1s(bf16) | P1(fp8)] = Hb @ W1T^T) ========
// grid (79, 8) = 632 blocks; XCD-chunked swizzle: each XCD gets ~10 row-tiles
// x all 8 col-slices -> A panel (1.25 MB) + W1T (1 MB) L2-resident per XCD.
__global__ __launch_bounds__(256) void k_gemm1_128(
    const u16* __restrict__ A, const u16* __restrict__ Bt,
    u16* __restrict__ C1s, u8* __restrict__ P1, int Mstore) {
    __shared__ __align__(16) u16 lA[3 * 128 * 32];
    __shared__ __align__(16) u16 lB[3 * 128 * 32];
    const int L = blockIdx.y * gridDim.x + blockIdx.x;
    const int T = xcd_swz(L, gridDim.x * gridDim.y);
    const int by = T & 7;                // col slice 0..7
    const int bcol = by * 128;
    const long brow = (long)(T >> 3) * 128;
    floatx4 acc[4][4];
    gemm_acc128(A, Bt, brow, bcol, acc, lA, lB);

    const int ln = threadIdx.x & 63;
    const int wv = threadIdx.x >> 6;
    const int wr = (wv >> 1) * 64;
    const int wc = (wv & 1) * 64;
    const int m0 = ln & 15;
    const int q4 = (ln >> 4) * 4;
    if (by < 4) {  // self half (cols 0..511) -> bf16, ld 512
#pragma unroll
        for (int i = 0; i < 4; ++i)
#pragma unroll
            for (int r = 0; r < 4; ++r) {
                long row = brow + wr + i * 16 + q4 + r;
                if (row < Mstore) {
#pragma unroll
                    for (int j = 0; j < 4; ++j)
                        C1s[row * 512 + (bcol + wc + j * 16 + m0)] = f2b(acc[i][j][r]);
                }
            }
    } else {       // agg half (cols 512..1023) -> fp8 e4m3 bytes, ld 512
        const int coff = bcol - 512;
#pragma unroll
        for (int i = 0; i < 4; ++i)
#pragma unroll
            for (int r = 0; r < 4; ++r) {
                long row = brow + wr + i * 16 + q4 + r;
                if (row < Mstore) {
#pragma unroll
                    for (int j = 0; j < 4; ++j) {
                        float v = acc[i][j][r];
                        int pk = __builtin_amdgcn_cvt_pk_fp8_f32(v, v, 0, false);
                        P1[row * 512 + (coff + wc + j * 16 + m0)] = (u8)(pk & 0xff);
                    }
                }
            }
    }
}

// ================= 64x128 GEMM core — depth-2 prefetch (GEMM2) ===================
// 3 global_load_lds per wave per tile -> steady-state vmcnt(6).
__device__ __forceinline__ void gemm_acc64(const u16* __restrict__ A,
                                           const u16* __restrict__ Bt,
                                           long brow, int bobs,
                                           floatx4 acc[4][2], u16* lA, u16* lB) {
    const int tid = threadIdx.x;
    const int wv = tid >> 6;
    const int ln = tid & 63;
    const int lrow = ln >> 2;
    const int lk = (ln & 3) * 8;
    const int m0 = ln & 15;
    const int kq = (ln >> 4) * 8;
    const int wc = wv * 32;

#pragma unroll
    for (int i = 0; i < 4; ++i)
#pragma unroll
        for (int j = 0; j < 2; ++j) acc[i][j] = (floatx4){0.f, 0.f, 0.f, 0.f};

    const u16* gA = A + (brow + wv * 16 + lrow) * 512 + lk;

    auto STAGE = [&](int kt, int sel) {
        u16* dA = lA + sel * 2048 + wv * 512;
        u16* dB = lB + sel * 4096;
        GLOAD_LDS16(gA + kt, dA);
#pragma unroll
        for (int ii = 0; ii < 2; ++ii) {
            const int c = ii * 4 + wv;
            GLOAD_LDS16(Bt + (long)(bobs + c * 16 + lrow) * 512 + kt + lk,
                        dB + c * 512);
        }
    };
    auto COMPUTE = [&](int sel) {
        const u16* rA = lA + sel * 2048;
        const u16* rB = lB + sel * 4096;
        bf16x8 af[4], bf[2];
#pragma unroll
        for (int i = 0; i < 4; ++i)
            af[i] = *(const bf16x8*)(rA + (i * 16 + m0) * 32 + kq);
#pragma unroll
        for (int j = 0; j < 2; ++j)
            bf[j] = *(const bf16x8*)(rB + (wc + j * 16 + m0) * 32 + kq);
#pragma unroll
        for (int i = 0; i < 4; ++i)
#pragma unroll
            for (int j = 0; j < 2; ++j)
                acc[i][j] = __builtin_amdgcn_mfma_f32_16x16x32_bf16(af[i], bf[j],
                                                                    acc[i][j], 0, 0, 0);
    };

    STAGE(0, 0);
    STAGE(32, 1);
    int cur = 0, nxt = 1, fut = 2;
    for (int t = 0; t < 14; ++t) {
        STAGE((t + 2) << 5, fut);
        asm volatile("s_waitcnt vmcnt(6)" ::: "memory");
        __builtin_amdgcn_s_barrier();
        COMPUTE(cur);
        asm volatile("s_waitcnt lgkmcnt(0)" ::: "memory");
        __builtin_amdgcn_s_barrier();
        int tmp = cur; cur = nxt; nxt = fut; fut = tmp;
    }
    asm volatile("s_waitcnt vmcnt(3)" ::: "memory");       // t = 14
    __builtin_amdgcn_s_barrier();
    COMPUTE(cur);
    asm volatile("s_waitcnt lgkmcnt(0)" ::: "memory");
    __builtin_amdgcn_s_barrier();
    asm volatile("s_waitcnt vmcnt(0)" ::: "memory");       // t = 15
    __builtin_amdgcn_s_barrier();
    COMPUTE(nxt);
}

// ================= D4: GEMM2 64x128 ([C2s|P2] = h1 @ W2T^T) ======================
__global__ __launch_bounds__(256) void k_gemm2_64(
    const u16* __restrict__ A, const u16* __restrict__ Bt,
    u16* __restrict__ C2s, u16* __restrict__ P2, int Mstore) {
    __shared__ __align__(16) u16 lA[3 * 64 * 32];
    __shared__ __align__(16) u16 lB[3 * 128 * 32];
    const int L = blockIdx.y * gridDim.x + blockIdx.x;
    const int T = xcd_swz(L, gridDim.x * gridDim.y);
    const int by = T & 1;
    const long brow = (long)(T >> 1) * 64;
    floatx4 acc[4][2];
    gemm_acc64(A, Bt, brow, by * 128, acc, lA, lB);

    u16* C = by ? P2 : C2s;
    const int ln = threadIdx.x & 63;
    const int wv = threadIdx.x >> 6;
    const int wc = wv * 32;
    const int m0 = ln & 15;
    const int q4 = (ln >> 4) * 4;
#pragma unroll
    for (int i = 0; i < 4; ++i)
#pragma unroll
        for (int r = 0; r < 4; ++r) {
            long row = brow + i * 16 + q4 + r;
            if (row < Mstore) {
#pragma unroll
                for (int j = 0; j < 2; ++j)
                    C[row * 128 + (wc + j * 16 + m0)] = f2b(acc[i][j][r]);
            }
        }
}

// ================= D3: h1 = relu(C1s + mean(P1fp8[nbrs]) + b1) ===================
// wave-per-node: one dwordx2 per edge; 8/4-deep gather unroll
__global__ __launch_bounds__(256) void agg_h1(const u8* __restrict__ P1,
                                              const u16* __restrict__ C1s,
                                              const u16* __restrict__ b1c,
                                              const int* __restrict__ cnt,
                                              const int* __restrict__ bucket,
                                              const int* __restrict__ nspill,
                                              const int* __restrict__ spill,
                                              u16* __restrict__ h1, int Nn) {
    const int n = blockIdx.x * 4 + (threadIdx.x >> 6);
    const int l = threadIdx.x & 63;
    if (n >= Nn) return;
    const int c = cnt[n];
    const int inb = c < CAP ? c : CAP;
    const int* bk = bucket + (long)n * CAP;
    float a0 = 0.f, a1 = 0.f, a2 = 0.f, a3 = 0.f;
    float a4 = 0.f, a5 = 0.f, a6 = 0.f, a7 = 0.f;
    int e = 0;
    for (; e + 7 < inb; e += 8) {
        u32x2 w[8];
#pragma unroll
        for (int q = 0; q < 8; ++q) {
            int s = bk[e + q];
            w[q] = *(const u32x2*)(P1 + (long)s * 512 + l * 8);
        }
#pragma unroll
        for (int q = 0; q < 8; ++q) {
            floatx2 f0 = __builtin_amdgcn_cvt_pk_f32_fp8(w[q][0], false);
            floatx2 f1 = __builtin_amdgcn_cvt_pk_f32_fp8(w[q][0], true);
            floatx2 f2 = __builtin_amdgcn_cvt_pk_f32_fp8(w[q][1], false);
            floatx2 f3 = __builtin_amdgcn_cvt_pk_f32_fp8(w[q][1], true);
            a0 += f0[0]; a1 += f0[1]; a2 += f1[0]; a3 += f1[1];
            a4 += f2[0]; a5 += f2[1]; a6 += f3[0]; a7 += f3[1];
        }
    }
    for (; e + 3 < inb; e += 4) {
        u32x2 w[4];
#pragma unroll
        for (int q = 0; q < 4; ++q) {
            int s = bk[e + q];
            w[q] = *(const u32x2*)(P1 + (long)s * 512 + l * 8);
        }
#pragma unroll
        for (int q = 0; q < 4; ++q) {
            floatx2 f0 = __builtin_amdgcn_cvt_pk_f32_fp8(w[q][0], false);
            floatx2 f1 = __builtin_amdgcn_cvt_pk_f32_fp8(w[q][0], true);
            floatx2 f2 = __builtin_amdgcn_cvt_pk_f32_fp8(w[q][1], false);
            floatx2 f3 = __builtin_amdgcn_cvt_pk_f32_fp8(w[q][1], true);
            a0 += f0[0]; a1 += f0[1]; a2 += f1[0]; a3 += f1[1];
            a4 += f2[0]; a5 += f2[1]; a6 += f3[0]; a7 += f3[1];
        }
    }
    for (; e < inb; ++e) {
        int s = bk[e];
        u32x2 w = *(const u32x2*)(P1 + (long)s * 512 + l * 8);
        floatx2 f0 = __builtin_amdgcn_cvt_pk_f32_fp8(w[0], false);
        floatx2 f1 = __builtin_amdgcn_cvt_pk_f32_fp8(w[0], true);
        floatx2 f2 = __builtin_amdgcn_cvt_pk_f32_fp8(w[1], false);
        floatx2 f3 = __builtin_amdgcn_cvt_pk_f32_fp8(w[1], true);
        a0 += f0[0]; a1 += f0[1]; a2 += f1[0]; a3 += f1[1];
        a4 += f2[0]; a5 += f2[1]; a6 += f3[0]; a7 += f3[1];
    }
    const int ns = *nspill;             // 0 in practice
    if (ns > 0) {
        int lim = ns < SPILLMAX ? ns : SPILLMAX;
        for (int q = 0; q < lim; ++q) {
            if (spill[2 * q] == n) {
                int s = spill[2 * q + 1];
                u32x2 w = *(const u32x2*)(P1 + (long)s * 512 + l * 8);
                floatx2 f0 = __builtin_amdgcn_cvt_pk_f32_fp8(w[0], false);
                floatx2 f1 = __builtin_amdgcn_cvt_pk_f32_fp8(w[0], true);
                floatx2 f2 = __builtin_amdgcn_cvt_pk_f32_fp8(w[1], false);
                floatx2 f3 = __builtin_amdgcn_cvt_pk_f32_fp8(w[1], true);
                a0 += f0[0]; a1 += f0[1]; a2 += f1[0]; a3 += f1[1];
                a4 += f2[0]; a5 += f2[1]; a6 += f3[0]; a7 += f3[1];
            }
        }
    }
    float inv = 1.0f / (float)(c > 1 ? c : 1);
    us8 sf = *(const us8*)(C1s + (long)n * 512 + l * 8);
    us8 bv = *(const us8*)(b1c + l * 8);
    us8 o;
    o[0] = f2b(fmaxf(b2f(sf[0]) + a0 * inv + b2f(bv[0]), 0.f));
    o[1] = f2b(fmaxf(b2f(sf[1]) + a1 * inv + b2f(bv[1]), 0.f));
    o[2] = f2b(fmaxf(b2f(sf[2]) + a2 * inv + b2f(bv[2]), 0.f));
    o[3] = f2b(fmaxf(b2f(sf[3]) + a3 * inv + b2f(bv[3]), 0.f));
    o[4] = f2b(fmaxf(b2f(sf[4]) + a4 * inv + b2f(bv[4]), 0.f));
    o[5] = f2b(fmaxf(b2f(sf[5]) + a5 * inv + b2f(bv[5]), 0.f));
    o[6] = f2b(fmaxf(b2f(sf[6]) + a6 * inv + b2f(bv[6]), 0.f));
    o[7] = f2b(fmaxf(b2f(sf[7]) + a7 * inv + b2f(bv[7]), 0.f));
    *(us8*)(h1 + (long)n * 512 + l * 8) = o;
}

// ================= D5: out = C2s + mean(P2[nbrs]) + b2 ===========================
__global__ __launch_bounds__(256) void agg_out(const u16* __restrict__ P2,
                                               const u16* __restrict__ C2s,
                                               const u16* __restrict__ b2c,
                                               const int* __restrict__ cnt,
                                               const int* __restrict__ bucket,
                                               const int* __restrict__ nspill,
                                               const int* __restrict__ spill,
                                               void* __restrict__ outv, int Nn,
                                               const int* __restrict__ flags) {
    const int n = blockIdx.x * 4 + (threadIdx.x >> 6);
    const int l = threadIdx.x & 63;
    if (n >= Nn) return;
    const int c = cnt[n];
    const int inb = c < CAP ? c : CAP;
    const int* bk = bucket + (long)n * CAP;
    float a0 = 0.f, a1 = 0.f;
    int e = 0;
    for (; e + 3 < inb; e += 4) {
        int s0 = bk[e], s1 = bk[e + 1], s2 = bk[e + 2], s3 = bk[e + 3];
        us2 v0 = *(const us2*)(P2 + (long)s0 * 128 + l * 2);
        us2 v1 = *(const us2*)(P2 + (long)s1 * 128 + l * 2);
        us2 v2 = *(const us2*)(P2 + (long)s2 * 128 + l * 2);
        us2 v3 = *(const us2*)(P2 + (long)s3 * 128 + l * 2);
        a0 += (b2f(v0[0]) + b2f(v1[0])) + (b2f(v2[0]) + b2f(v3[0]));
        a1 += (b2f(v0[1]) + b2f(v1[1])) + (b2f(v2[1]) + b2f(v3[1]));
    }
    for (; e < inb; ++e) {
        int s0 = bk[e];
        us2 v0 = *(const us2*)(P2 + (long)s0 * 128 + l * 2);
        a0 += b2f(v0[0]); a1 += b2f(v0[1]);
    }
    const int ns = *nspill;
    if (ns > 0) {
        int lim = ns < SPILLMAX ? ns : SPILLMAX;
        for (int q = 0; q < lim; ++q) {
            if (spill[2 * q] == n) {
                int s0 = spill[2 * q + 1];
                us2 v0 = *(const us2*)(P2 + (long)s0 * 128 + l * 2);
                a0 += b2f(v0[0]); a1 += b2f(v0[1]);
            }
        }
    }
    float inv = 1.0f / (float)(c > 1 ? c : 1);
    us2 sf = *(const us2*)(C2s + (long)n * 128 + l * 2);
    us2 bv = *(const us2*)(b2c + l * 2);
    float o0 = b2f(sf[0]) + a0 * inv + b2f(bv[0]);
    float o1 = b2f(sf[1]) + a1 * inv + b2f(bv[1]);
    if (flags[0]) {
        float* o = (float*)outv + (long)n * 128 + l * 2;
        o[0] = o0; o[1] = o1;
    } else {
        us2 ob; ob[0] = f2b(o0); ob[1] = f2b(o1);
        *(us2*)((u16*)outv + (long)n * 128 + l * 2) = ob;
    }
}

// ================= launch ========================================================
extern "C" void kernel_launch(void* const* d_in, const int* in_sizes, int n_in,
                              void* d_out, int out_size, void* d_ws, size_t ws_size,
                              hipStream_t stream) {
    const int D = 512, NCLS = 128;
    const int Nn = in_sizes[0] / D;            // 10000
    const int E  = in_sizes[5];                // 160000
    const int mtiles = (Nn + 127) / 128;       // 79
    const int mt64 = (Nn + 63) / 64;           // 157
    const int Mpad = mtiles * 128;             // 10112
    const int nFill = (E + 255) / 256;         // 625
    const int nHb = (Nn * D / 8 + 255) / 256;  // 2500

    const int* src = (const int*)d_in[5];
    const int* dst = (const int*)d_in[6];

    char* p = (char*)d_ws;
    u16* Hb  = (u16*)p; p += (size_t)Mpad * D * 2;
    u16* h1  = (u16*)p; p += (size_t)Mpad * D * 2;
    u16* C1s = (u16*)p; p += (size_t)Mpad * D * 2;
    u8*  P1  = (u8*)p;  p += (size_t)Mpad * D;        // fp8 e4m3
    u16* C2s = (u16*)p; p += (size_t)Mpad * NCLS * 2;
    u16* P2  = (u16*)p; p += (size_t)Mpad * NCLS * 2;
    u16* W1T = (u16*)p; p += (size_t)1024 * D * 2;
    u16* W2T = (u16*)p; p += (size_t)256 * D * 2;
    u16* b1c = (u16*)p; p += 1024;
    u16* b2c = (u16*)p; p += 1024;
    int* flags  = (int*)p; p += 256;
    int* cnt    = (int*)p; p += (size_t)(Nn + 60) * 4;
    int* nspill = cnt + Nn;
    int* bucket = (int*)p; p += (size_t)Nn * CAP * 4;
    int* spill  = (int*)p; p += (size_t)SPILLMAX * 2 * 4;

    hipMemsetAsync(cnt, 0, (size_t)(Nn + 60) * 4, stream);

    // D1: buckets + all conversions
    k_d1<<<nFill + nHb + 641, 256, 0, stream>>>(
        src, dst, E, Nn, cnt, bucket, nspill, spill,
        d_in[0], d_in[1], d_in[2], d_in[3], d_in[4],
        Hb, W1T, W2T, b1c, b2c, flags, nFill, nHb);

    // D2: [C1s(bf16) | P1(fp8)] = Hb @ W1T^T  [128x128 tiles, 632 blocks, depth-2]
    k_gemm1_128<<<dim3(mtiles, 8), 256, 0, stream>>>(Hb, W1T, C1s, P1, Nn);

    // D3: h1 = relu(C1s + mean(P1[nbrs]) + b1)  [wave-per-node]
    agg_h1<<<(Nn + 3) / 4, 256, 0, stream>>>(P1, C1s, b1c, cnt, bucket,
                                             nspill, spill, h1, Nn);

    // D4: [C2s|P2] = h1 @ W2T^T  [64x128 tiles, 314 blocks, depth-2]
    k_gemm2_64<<<dim3(mt64, 2), 256, 0, stream>>>(h1, W2T, C2s, P2, Nn);

    // D5: out = C2s + mean(P2[nbrs]) + b2
    agg_out<<<(Nn + 3) / 4, 256, 0, stream>>>(P2, C2s, b2c, cnt, bucket,
                                              nspill, spill, d_out, Nn, flags);
}

// Round 3
// 148.064 us; speedup vs baseline: 1.0718x; 1.0006x over previous
//
#include <hip/hip_runtime.h>

typedef unsigned short u16;
typedef unsigned char u8;
typedef __attribute__((ext_vector_type(2))) float floatx2;
typedef __attribute__((ext_vector_type(4))) float floatx4;
typedef __attribute__((ext_vector_type(8))) __bf16 bf16x8;
typedef __attribute__((ext_vector_type(2))) unsigned short us2;
typedef __attribute__((ext_vector_type(4))) unsigned short us4;
typedef __attribute__((ext_vector_type(8))) unsigned short us8;
typedef __attribute__((ext_vector_type(2))) unsigned int u32x2;

static __device__ __forceinline__ float b2f(u16 v) {
    union { unsigned u; float f; } x; x.u = ((unsigned)v) << 16; return x.f;
}
static __device__ __forceinline__ u16 f2b(float f) {
    union { float f; unsigned u; } x; x.f = f;
    unsigned u = x.u;
    return (u16)((u + 0x7fffu + ((u >> 16) & 1u)) >> 16);
}

#define GLOAD_LDS16(g, l) __builtin_amdgcn_global_load_lds( \
    (const __attribute__((address_space(1))) void*)(g),     \
    (__attribute__((address_space(3))) void*)(l), 16, 0, 0)

#define CAP 64
#define SPILLMAX 4096

// Per-block dtype self-detection (see R5 notes): P(misdetect fp32) ~ 1e-65.
static __device__ __forceinline__ int detect_blk(const u16* __restrict__ p,
                                                 int nelem, int* sh) {
    if (threadIdx.x == 0) *sh = 0;
    __syncthreads();
    const int lim = nelem < 512 ? nelem : 512;
    int found = 0;
    for (int j = threadIdx.x; 2 * j < lim; j += 256) {
        unsigned v = p[2 * j] & 0x7fffu;
        if (v >= 0x4280u) found = 1;  // |bf16(bits)| >= 64.0
    }
    if (found) atomicOr(sh, 1);
    __syncthreads();
    return *sh;
}

// Bijective XCD-chunked swizzle (m204): blocks with the same output-tile row
// group land on one XCD so shared A-tiles hit that XCD's L2.
static __device__ __forceinline__ int xcd_swz(int L, int nwg) {
    const int q = nwg >> 3, r = nwg & 7;
    const int x = L & 7, i = L >> 3;
    return (x < r ? x * (q + 1) : r * (q + 1) + (x - r) * q) + i;
}

// ================= D1: buckets + all conversions (self-detecting) ================
__global__ __launch_bounds__(256) void k_d1(
    const int* __restrict__ src, const int* __restrict__ dst, int E, int Nn,
    int* __restrict__ cnt, int* __restrict__ bucket,
    int* __restrict__ nspill, int* __restrict__ spill,
    const void* __restrict__ h, const void* __restrict__ W1,
    const void* __restrict__ b1, const void* __restrict__ W2,
    const void* __restrict__ b2,
    u16* __restrict__ Hb, u16* __restrict__ W1T, u16* __restrict__ W2T,
    u16* __restrict__ b1c, u16* __restrict__ b2c, int* __restrict__ flags,
    int nFill, int nHb) {
    __shared__ u16 tile[32][33];
    __shared__ int sh;
    const int b = blockIdx.x;
    const int t = threadIdx.x;

    if (b < nFill) {  // -------- bucket fill --------
        int e = b * 256 + t;
        if (e < E) {
            int d = dst[e], s = src[e];
            if ((unsigned)d < (unsigned)Nn && (unsigned)s < (unsigned)Nn) {
                int p = atomicAdd(&cnt[d], 1);
                if (p < CAP) bucket[d * CAP + p] = s;
                else {
                    int q = atomicAdd(nspill, 1);
                    if (q < SPILLMAX) { spill[2 * q] = d; spill[2 * q + 1] = s; }
                }
            }
        }
        return;
    }
    if (b < nFill + nHb) {  // -------- Hb cvt --------
        const int f = detect_blk((const u16*)h, Nn * 512, &sh);
        int i = ((b - nFill) * 256 + t) * 8;
        if (i >= Nn * 512) return;
        if (f) {
            const floatx4* s = (const floatx4*)((const float*)h + i);
            floatx4 v0 = s[0], v1 = s[1];
            us8 o;
            o[0] = f2b(v0[0]); o[1] = f2b(v0[1]); o[2] = f2b(v0[2]); o[3] = f2b(v0[3]);
            o[4] = f2b(v1[0]); o[5] = f2b(v1[1]); o[6] = f2b(v1[2]); o[7] = f2b(v1[3]);
            *(us8*)(Hb + i) = o;
        } else {
            *(us8*)(Hb + i) = *(const us8*)((const u16*)h + i);
        }
        return;
    }
    if (b < nFill + nHb + 512) {  // -------- W1 [1024,512] -> W1T [1024,512] --------
        const int f = detect_blk((const u16*)W1, 1024 * 512, &sh);
        int sub = b - nFill - nHb;
        int half = sub >> 8, idx = sub & 255;
        const int bx = (idx & 15) * 32, by = (idx >> 4) * 32;
        const int koff = half * 512, noff = half * 512;
        const int tx = t & 31, ty = t >> 5;
        for (int i = ty; i < 32; i += 8) {
            long id = (long)(koff + by + i) * 512 + (bx + tx);
            tile[i][tx] = f ? f2b(((const float*)W1)[id]) : ((const u16*)W1)[id];
        }
        __syncthreads();
        for (int i = ty; i < 32; i += 8)
            W1T[(long)(noff + bx + i) * 512 + (by + tx)] = tile[tx][i];
        return;
    }
    if (b < nFill + nHb + 640) {  // -------- W2 [1024,128] -> W2T [256,512] --------
        const int f = detect_blk((const u16*)W2, 1024 * 128, &sh);
        int sub = b - nFill - nHb - 512;
        int half = sub >> 6, idx = sub & 63;
        const int bx = (idx & 3) * 32, by = (idx >> 2) * 32;
        const int koff = half * 512, noff = half * 128;
        const int tx = t & 31, ty = t >> 5;
        for (int i = ty; i < 32; i += 8) {
            long id = (long)(koff + by + i) * 128 + (bx + tx);
            tile[i][tx] = f ? f2b(((const float*)W2)[id]) : ((const u16*)W2)[id];
        }
        __syncthreads();
        for (int i = ty; i < 32; i += 8)
            W2T[(long)(noff + bx + i) * 512 + (by + tx)] = tile[tx][i];
        return;
    }
    // -------- biases + out-dtype flag --------
    {
        const int f1 = detect_blk((const u16*)b1, 512, &sh);
        for (int i = t; i < 512; i += 256)
            b1c[i] = f1 ? f2b(((const float*)b1)[i]) : ((const u16*)b1)[i];
        const int f2 = detect_blk((const u16*)b2, 128, &sh);
        if (t < 128)
            b2c[t] = f2 ? f2b(((const float*)b2)[t]) : ((const u16*)b2)[t];
        const int fh = detect_blk((const u16*)h, Nn * 512, &sh);
        if (t == 0) flags[0] = fh;
    }
}

// ================= 64x128 GEMM core — 2-phase dbuf, vmcnt(3) =====================
// 4 waves, wave wv covers cols wv*32..+32: acc 4x2, 8 MFMA/k-iter. 3
// global_load_lds per wave per tile -> steady-state vmcnt(3). LDS 24 KB ->
// 6 blocks/CU co-residency ceiling (TLP is the design point: grid >> CUs).
// Per-output K order identical to all previous cores -> bit-identical.
__device__ __forceinline__ void gemm_acc64(const u16* __restrict__ A,
                                           const u16* __restrict__ Bt,
                                           long brow, int bobs,
                                           floatx4 acc[4][2], u16* lA, u16* lB) {
    const int tid = threadIdx.x;
    const int wv = tid >> 6;
    const int ln = tid & 63;
    const int lrow = ln >> 2;
    const int lk = (ln & 3) * 8;
    const int m0 = ln & 15;
    const int kq = (ln >> 4) * 8;
    const int wc = wv * 32;

#pragma unroll
    for (int i = 0; i < 4; ++i)
#pragma unroll
        for (int j = 0; j < 2; ++j) acc[i][j] = (floatx4){0.f, 0.f, 0.f, 0.f};

    const u16* gA = A + (brow + wv * 16 + lrow) * 512 + lk;

    auto STAGE = [&](int kt, int sel) {
        u16* dA = lA + sel * 2048 + wv * 512;
        u16* dB = lB + sel * 4096;
        GLOAD_LDS16(gA + kt, dA);
#pragma unroll
        for (int ii = 0; ii < 2; ++ii) {
            const int c = ii * 4 + wv;
            GLOAD_LDS16(Bt + (long)(bobs + c * 16 + lrow) * 512 + kt + lk,
                        dB + c * 512);
        }
    };
    auto COMPUTE = [&](int sel) {
        const u16* rA = lA + sel * 2048;
        const u16* rB = lB + sel * 4096;
        bf16x8 af[4], bf[2];
#pragma unroll
        for (int i = 0; i < 4; ++i)
            af[i] = *(const bf16x8*)(rA + (i * 16 + m0) * 32 + kq);
#pragma unroll
        for (int j = 0; j < 2; ++j)
            bf[j] = *(const bf16x8*)(rB + (wc + j * 16 + m0) * 32 + kq);
#pragma unroll
        for (int i = 0; i < 4; ++i)
#pragma unroll
            for (int j = 0; j < 2; ++j)
                acc[i][j] = __builtin_amdgcn_mfma_f32_16x16x32_bf16(af[i], bf[j],
                                                                    acc[i][j], 0, 0, 0);
    };

    STAGE(0, 0);
    for (int t = 0; t < 15; ++t) {
        const int sel = t & 1;
        STAGE((t + 1) << 5, sel ^ 1);                      // prefetch next tile
        asm volatile("s_waitcnt vmcnt(3)" ::: "memory");   // own tile-t loads done
        __builtin_amdgcn_s_barrier();                      // => all waves' done
        COMPUTE(sel);
        asm volatile("s_waitcnt lgkmcnt(0)" ::: "memory"); // LDS reads retired
        __builtin_amdgcn_s_barrier();
    }
    asm volatile("s_waitcnt vmcnt(0)" ::: "memory");       // t = 15
    __builtin_amdgcn_s_barrier();
    COMPUTE(1);
}

// ================= D2: GEMM1 64x128 ([C1s(bf16) | P1(fp8)] = Hb @ W1T^T) =========
// grid (157, 8) = 1256 blocks (~4.9/CU, all co-resident at 24 KB LDS) -> ~20
// waves/CU during GEMM1. XCD swizzle keeps each XCD's A rows + W1T in its L2.
__global__ __launch_bounds__(256) void k_gemm1_64(
    const u16* __restrict__ A, const u16* __restrict__ Bt,
    u16* __restrict__ C1s, u8* __restrict__ P1, int Mstore) {
    __shared__ __align__(16) u16 lA[2 * 64 * 32];
    __shared__ __align__(16) u16 lB[2 * 128 * 32];
    const int L = blockIdx.y * gridDim.x + blockIdx.x;
    const int T = xcd_swz(L, gridDim.x * gridDim.y);
    const int by = T & 7;                // col slice 0..7 (128 cols each)
    const int bcol = by * 128;
    const long brow = (long)(T >> 3) * 64;
    floatx4 acc[4][2];
    gemm_acc64(A, Bt, brow, bcol, acc, lA, lB);

    const int ln = threadIdx.x & 63;
    const int wv = threadIdx.x >> 6;
    const int wc = wv * 32;
    const int m0 = ln & 15;
    const int q4 = (ln >> 4) * 4;
    if (by < 4) {  // self half (cols 0..511) -> bf16, ld 512
#pragma unroll
        for (int i = 0; i < 4; ++i)
#pragma unroll
            for (int r = 0; r < 4; ++r) {
                long row = brow + i * 16 + q4 + r;
                if (row < Mstore) {
#pragma unroll
                    for (int j = 0; j < 2; ++j)
                        C1s[row * 512 + (bcol + wc + j * 16 + m0)] = f2b(acc[i][j][r]);
                }
            }
    } else {       // agg half (cols 512..1023) -> fp8 e4m3 bytes, ld 512
        const int coff = bcol - 512;
#pragma unroll
        for (int i = 0; i < 4; ++i)
#pragma unroll
            for (int r = 0; r < 4; ++r) {
                long row = brow + i * 16 + q4 + r;
                if (row < Mstore) {
#pragma unroll
                    for (int j = 0; j < 2; ++j) {
                        float v = acc[i][j][r];
                        int pk = __builtin_amdgcn_cvt_pk_fp8_f32(v, v, 0, false);
                        P1[row * 512 + (coff + wc + j * 16 + m0)] = (u8)(pk & 0xff);
                    }
                }
            }
    }
}

// ================= D4: GEMM2 64x128 ([C2s|P2] = h1 @ W2T^T) ======================
__global__ __launch_bounds__(256) void k_gemm2_64(
    const u16* __restrict__ A, const u16* __restrict__ Bt,
    u16* __restrict__ C2s, u16* __restrict__ P2, int Mstore) {
    __shared__ __align__(16) u16 lA[2 * 64 * 32];
    __shared__ __align__(16) u16 lB[2 * 128 * 32];
    const int L = blockIdx.y * gridDim.x + blockIdx.x;
    const int T = xcd_swz(L, gridDim.x * gridDim.y);
    const int by = T & 1;
    const long brow = (long)(T >> 1) * 64;
    floatx4 acc[4][2];
    gemm_acc64(A, Bt, brow, by * 128, acc, lA, lB);

    u16* C = by ? P2 : C2s;
    const int ln = threadIdx.x & 63;
    const int wv = threadIdx.x >> 6;
    const int wc = wv * 32;
    const int m0 = ln & 15;
    const int q4 = (ln >> 4) * 4;
#pragma unroll
    for (int i = 0; i < 4; ++i)
#pragma unroll
        for (int r = 0; r < 4; ++r) {
            long row = brow + i * 16 + q4 + r;
            if (row < Mstore) {
#pragma unroll
                for (int j = 0; j < 2; ++j)
                    C[row * 128 + (wc + j * 16 + m0)] = f2b(acc[i][j][r]);
            }
        }
}

// ================= D3: h1 = relu(C1s + mean(P1fp8[nbrs]) + b1) ===================
// wave-per-node: one dwordx2 per edge; 8/4-deep gather unroll
__global__ __launch_bounds__(256) void agg_h1(const u8* __restrict__ P1,
                                              const u16* __restrict__ C1s,
                                              const u16* __restrict__ b1c,
                                              const int* __restrict__ cnt,
                                              const int* __restrict__ bucket,
                                              const int* __restrict__ nspill,
                                              const int* __restrict__ spill,
                                              u16* __restrict__ h1, int Nn) {
    const int n = blockIdx.x * 4 + (threadIdx.x >> 6);
    const int l = threadIdx.x & 63;
    if (n >= Nn) return;
    const int c = cnt[n];
    const int inb = c < CAP ? c : CAP;
    const int* bk = bucket + (long)n * CAP;
    float a0 = 0.f, a1 = 0.f, a2 = 0.f, a3 = 0.f;
    float a4 = 0.f, a5 = 0.f, a6 = 0.f, a7 = 0.f;
    int e = 0;
    for (; e + 7 < inb; e += 8) {
        u32x2 w[8];
#pragma unroll
        for (int q = 0; q < 8; ++q) {
            int s = bk[e + q];
            w[q] = *(const u32x2*)(P1 + (long)s * 512 + l * 8);
        }
#pragma unroll
        for (int q = 0; q < 8; ++q) {
            floatx2 f0 = __builtin_amdgcn_cvt_pk_f32_fp8(w[q][0], false);
            floatx2 f1 = __builtin_amdgcn_cvt_pk_f32_fp8(w[q][0], true);
            floatx2 f2 = __builtin_amdgcn_cvt_pk_f32_fp8(w[q][1], false);
            floatx2 f3 = __builtin_amdgcn_cvt_pk_f32_fp8(w[q][1], true);
            a0 += f0[0]; a1 += f0[1]; a2 += f1[0]; a3 += f1[1];
            a4 += f2[0]; a5 += f2[1]; a6 += f3[0]; a7 += f3[1];
        }
    }
    for (; e + 3 < inb; e += 4) {
        u32x2 w[4];
#pragma unroll
        for (int q = 0; q < 4; ++q) {
            int s = bk[e + q];
            w[q] = *(const u32x2*)(P1 + (long)s * 512 + l * 8);
        }
#pragma unroll
        for (int q = 0; q < 4; ++q) {
            floatx2 f0 = __builtin_amdgcn_cvt_pk_f32_fp8(w[q][0], false);
            floatx2 f1 = __builtin_amdgcn_cvt_pk_f32_fp8(w[q][0], true);
            floatx2 f2 = __builtin_amdgcn_cvt_pk_f32_fp8(w[q][1], false);
            floatx2 f3 = __builtin_amdgcn_cvt_pk_f32_fp8(w[q][1], true);
            a0 += f0[0]; a1 += f0[1]; a2 += f1[0]; a3 += f1[1];
            a4 += f2[0]; a5 += f2[1]; a6 += f3[0]; a7 += f3[1];
        }
    }
    for (; e < inb; ++e) {
        int s = bk[e];
        u32x2 w = *(const u32x2*)(P1 + (long)s * 512 + l * 8);
        floatx2 f0 = __builtin_amdgcn_cvt_pk_f32_fp8(w[0], false);
        floatx2 f1 = __builtin_amdgcn_cvt_pk_f32_fp8(w[0], true);
        floatx2 f2 = __builtin_amdgcn_cvt_pk_f32_fp8(w[1], false);
        floatx2 f3 = __builtin_amdgcn_cvt_pk_f32_fp8(w[1], true);
        a0 += f0[0]; a1 += f0[1]; a2 += f1[0]; a3 += f1[1];
        a4 += f2[0]; a5 += f2[1]; a6 += f3[0]; a7 += f3[1];
    }
    const int ns = *nspill;             // 0 in practice
    if (ns > 0) {
        int lim = ns < SPILLMAX ? ns : SPILLMAX;
        for (int q = 0; q < lim; ++q) {
            if (spill[2 * q] == n) {
                int s = spill[2 * q + 1];
                u32x2 w = *(const u32x2*)(P1 + (long)s * 512 + l * 8);
                floatx2 f0 = __builtin_amdgcn_cvt_pk_f32_fp8(w[0], false);
                floatx2 f1 = __builtin_amdgcn_cvt_pk_f32_fp8(w[0], true);
                floatx2 f2 = __builtin_amdgcn_cvt_pk_f32_fp8(w[1], false);
                floatx2 f3 = __builtin_amdgcn_cvt_pk_f32_fp8(w[1], true);
                a0 += f0[0]; a1 += f0[1]; a2 += f1[0]; a3 += f1[1];
                a4 += f2[0]; a5 += f2[1]; a6 += f3[0]; a7 += f3[1];
            }
        }
    }
    float inv = 1.0f / (float)(c > 1 ? c : 1);
    us8 sf = *(const us8*)(C1s + (long)n * 512 + l * 8);
    us8 bv = *(const us8*)(b1c + l * 8);
    us8 o;
    o[0] = f2b(fmaxf(b2f(sf[0]) + a0 * inv + b2f(bv[0]), 0.f));
    o[1] = f2b(fmaxf(b2f(sf[1]) + a1 * inv + b2f(bv[1]), 0.f));
    o[2] = f2b(fmaxf(b2f(sf[2]) + a2 * inv + b2f(bv[2]), 0.f));
    o[3] = f2b(fmaxf(b2f(sf[3]) + a3 * inv + b2f(bv[3]), 0.f));
    o[4] = f2b(fmaxf(b2f(sf[4]) + a4 * inv + b2f(bv[4]), 0.f));
    o[5] = f2b(fmaxf(b2f(sf[5]) + a5 * inv + b2f(bv[5]), 0.f));
    o[6] = f2b(fmaxf(b2f(sf[6]) + a6 * inv + b2f(bv[6]), 0.f));
    o[7] = f2b(fmaxf(b2f(sf[7]) + a7 * inv + b2f(bv[7]), 0.f));
    *(us8*)(h1 + (long)n * 512 + l * 8) = o;
}

// ================= D5: out = C2s + mean(P2[nbrs]) + b2 ===========================
__global__ __launch_bounds__(256) void agg_out(const u16* __restrict__ P2,
                                               const u16* __restrict__ C2s,
                                               const u16* __restrict__ b2c,
                                               const int* __restrict__ cnt,
                                               const int* __restrict__ bucket,
                                               const int* __restrict__ nspill,
                                               const int* __restrict__ spill,
                                               void* __restrict__ outv, int Nn,
                                               const int* __restrict__ flags) {
    const int n = blockIdx.x * 4 + (threadIdx.x >> 6);
    const int l = threadIdx.x & 63;
    if (n >= Nn) return;
    const int c = cnt[n];
    const int inb = c < CAP ? c : CAP;
    const int* bk = bucket + (long)n * CAP;
    float a0 = 0.f, a1 = 0.f;
    int e = 0;
    for (; e + 3 < inb; e += 4) {
        int s0 = bk[e], s1 = bk[e + 1], s2 = bk[e + 2], s3 = bk[e + 3];
        us2 v0 = *(const us2*)(P2 + (long)s0 * 128 + l * 2);
        us2 v1 = *(const us2*)(P2 + (long)s1 * 128 + l * 2);
        us2 v2 = *(const us2*)(P2 + (long)s2 * 128 + l * 2);
        us2 v3 = *(const us2*)(P2 + (long)s3 * 128 + l * 2);
        a0 += (b2f(v0[0]) + b2f(v1[0])) + (b2f(v2[0]) + b2f(v3[0]));
        a1 += (b2f(v0[1]) + b2f(v1[1])) + (b2f(v2[1]) + b2f(v3[1]));
    }
    for (; e < inb; ++e) {
        int s0 = bk[e];
        us2 v0 = *(const us2*)(P2 + (long)s0 * 128 + l * 2);
        a0 += b2f(v0[0]); a1 += b2f(v0[1]);
    }
    const int ns = *nspill;
    if (ns > 0) {
        int lim = ns < SPILLMAX ? ns : SPILLMAX;
        for (int q = 0; q < lim; ++q) {
            if (spill[2 * q] == n) {
                int s0 = spill[2 * q + 1];
                us2 v0 = *(const us2*)(P2 + (long)s0 * 128 + l * 2);
                a0 += b2f(v0[0]); a1 += b2f(v0[1]);
            }
        }
    }
    float inv = 1.0f / (float)(c > 1 ? c : 1);
    us2 sf = *(const us2*)(C2s + (long)n * 128 + l * 2);
    us2 bv = *(const us2*)(b2c + l * 2);
    float o0 = b2f(sf[0]) + a0 * inv + b2f(bv[0]);
    float o1 = b2f(sf[1]) + a1 * inv + b2f(bv[1]);
    if (flags[0]) {
        float* o = (float*)outv + (long)n * 128 + l * 2;
        o[0] = o0; o[1] = o1;
    } else {
        us2 ob; ob[0] = f2b(o0); ob[1] = f2b(o1);
        *(us2*)((u16*)outv + (long)n * 128 + l * 2) = ob;
    }
}

// ================= launch ========================================================
extern "C" void kernel_launch(void* const* d_in, const int* in_sizes, int n_in,
                              void* d_out, int out_size, void* d_ws, size_t ws_size,
                              hipStream_t stream) {
    const int D = 512, NCLS = 128;
    const int Nn = in_sizes[0] / D;            // 10000
    const int E  = in_sizes[5];                // 160000
    const int mtiles = (Nn + 127) / 128;       // 79
    const int mt64 = (Nn + 63) / 64;           // 157
    const int Mpad = mtiles * 128;             // 10112
    const int nFill = (E + 255) / 256;         // 625
    const int nHb = (Nn * D / 8 + 255) / 256;  // 2500

    const int* src = (const int*)d_in[5];
    const int* dst = (const int*)d_in[6];

    char* p = (char*)d_ws;
    u16* Hb  = (u16*)p; p += (size_t)Mpad * D * 2;
    u16* h1  = (u16*)p; p += (size_t)Mpad * D * 2;
    u16* C1s = (u16*)p; p += (size_t)Mpad * D * 2;
    u8*  P1  = (u8*)p;  p += (size_t)Mpad * D;        // fp8 e4m3
    u16* C2s = (u16*)p; p += (size_t)Mpad * NCLS * 2;
    u16* P2  = (u16*)p; p += (size_t)Mpad * NCLS * 2;
    u16* W1T = (u16*)p; p += (size_t)1024 * D * 2;
    u16* W2T = (u16*)p; p += (size_t)256 * D * 2;
    u16* b1c = (u16*)p; p += 1024;
    u16* b2c = (u16*)p; p += 1024;
    int* flags  = (int*)p; p += 256;
    int* cnt    = (int*)p; p += (size_t)(Nn + 60) * 4;
    int* nspill = cnt + Nn;
    int* bucket = (int*)p; p += (size_t)Nn * CAP * 4;
    int* spill  = (int*)p; p += (size_t)SPILLMAX * 2 * 4;

    hipMemsetAsync(cnt, 0, (size_t)(Nn + 60) * 4, stream);

    // D1: buckets + all conversions
    k_d1<<<nFill + nHb + 641, 256, 0, stream>>>(
        src, dst, E, Nn, cnt, bucket, nspill, spill,
        d_in[0], d_in[1], d_in[2], d_in[3], d_in[4],
        Hb, W1T, W2T, b1c, b2c, flags, nFill, nHb);

    // D2: [C1s(bf16) | P1(fp8)] = Hb @ W1T^T  [64x128 tiles, 1256 blocks]
    k_gemm1_64<<<dim3(mt64, 8), 256, 0, stream>>>(Hb, W1T, C1s, P1, Nn);

    // D3: h1 = relu(C1s + mean(P1[nbrs]) + b1)  [wave-per-node]
    agg_h1<<<(Nn + 3) / 4, 256, 0, stream>>>(P1, C1s, b1c, cnt, bucket,
                                             nspill, spill, h1, Nn);

    // D4: [C2s|P2] = h1 @ W2T^T  [64x128 tiles, 314 blocks]
    k_gemm2_64<<<dim3(mt64, 2), 256, 0, stream>>>(h1, W2T, C2s, P2, Nn);

    // D5: out = C2s + mean(P2[nbrs]) + b2
    agg_out<<<(Nn + 3) / 4, 256, 0, stream>>>(P2, C2s, b2c, cnt, bucket,
                                              nspill, spill, d_out, Nn, flags);
}